// Round 1
// baseline (3780.104 us; speedup 1.0000x reference)
//
#include <hip/hip_runtime.h>

#define DIM 128

// ---------------- degree / dinv ----------------

__global__ __launch_bounds__(256) void k_init_deg(float* __restrict__ deg, int n) {
    int i = blockIdx.x * 256 + threadIdx.x;
    if (i < n) deg[i] = 1.0f;   // self-loop contributes 1 to every node's degree
}

__global__ __launch_bounds__(256) void k_count_deg(const int* __restrict__ dst,
                                                   float* __restrict__ deg, int E) {
    int e = blockIdx.x * 256 + threadIdx.x;
    if (e < E) atomicAdd(&deg[dst[e]], 1.0f);
}

__global__ __launch_bounds__(256) void k_dinv(float* __restrict__ deg, int n) {
    int i = blockIdx.x * 256 + threadIdx.x;
    if (i < n) {
        float d = deg[i];
        deg[i] = d > 0.0f ? rsqrtf(d) : 0.0f;   // in-place: deg -> dinv
    }
}

// ---------------- HW = H @ W  (H [n,128] fp32, W [128,128] fp32) ----------------
// Block: 256 threads, 16 rows. W staged in LDS (64KB), H rows staged padded
// (stride 132 keeps float4 alignment, breaks the 16-way row-bank collision).
__global__ __launch_bounds__(256) void k_gemm(const float* __restrict__ H,
                                              const float* __restrict__ W,
                                              float* __restrict__ HW, int n) {
    __shared__ float sW[DIM * DIM];
    __shared__ float sH[16 * 132];
    int tid = threadIdx.x;

    const float4* W4 = (const float4*)W;
    float4* sW4 = (float4*)sW;
#pragma unroll
    for (int i = 0; i < 16; ++i) sW4[tid + i * 256] = W4[tid + i * 256];

    int row0 = blockIdx.x * 16;
#pragma unroll
    for (int i = 0; i < 2; ++i) {
        int idx = tid + i * 256;     // 0..511 float4 slots (16 rows x 32)
        int r = idx >> 5;
        int c = idx & 31;
        int rg = row0 + r;
        float4 v = make_float4(0.f, 0.f, 0.f, 0.f);
        if (rg < n) v = ((const float4*)(H + (size_t)rg * DIM))[c];
        *(float4*)(sH + r * 132 + c * 4) = v;
    }
    __syncthreads();

    int rl = tid >> 4;      // 0..15 row within block
    int jg = tid & 15;      // 0..15 column group (8 cols each)
    float acc[8] = {0, 0, 0, 0, 0, 0, 0, 0};
    const float* hrow = sH + rl * 132;
#pragma unroll 4
    for (int k = 0; k < DIM; ++k) {
        float hv = hrow[k];
        const float* w = sW + k * DIM + jg * 8;
        float4 w0 = *(const float4*)(w);
        float4 w1 = *(const float4*)(w + 4);
        acc[0] += hv * w0.x; acc[1] += hv * w0.y;
        acc[2] += hv * w0.z; acc[3] += hv * w0.w;
        acc[4] += hv * w1.x; acc[5] += hv * w1.y;
        acc[6] += hv * w1.z; acc[7] += hv * w1.w;
    }
    int rg = row0 + rl;
    if (rg < n) {
        float* o = HW + (size_t)rg * DIM + jg * 8;
        *(float4*)o       = make_float4(acc[0], acc[1], acc[2], acc[3]);
        *(float4*)(o + 4) = make_float4(acc[4], acc[5], acc[6], acc[7]);
    }
}

// ---------------- out[i][:] = dinv[i]^2 * HW[i][:]  (self-loop, also inits out) ----------------
__global__ __launch_bounds__(256) void k_selfinit(const float* __restrict__ HW,
                                                  const float* __restrict__ dinv,
                                                  float* __restrict__ out, int n) {
    int idx = blockIdx.x * 256 + threadIdx.x;   // over n*32 float4
    if (idx >= n * 32) return;
    int i = idx >> 5;
    float dv = dinv[i];
    float s = dv * dv;
    float4 v = ((const float4*)HW)[idx];
    ((float4*)out)[idx] = make_float4(s * v.x, s * v.y, s * v.z, s * v.w);
}

// ---------------- edge scatter: out[dst] += dinv[src]*dinv[dst] * HW[src] ----------------
// 32 lanes per edge, float4 gather, 4 fp32 atomics per lane.
__global__ __launch_bounds__(256) void k_scatter(const float* __restrict__ HW,
                                                 const int* __restrict__ src,
                                                 const int* __restrict__ dst,
                                                 const float* __restrict__ dinv,
                                                 float* __restrict__ out, int E) {
    int t = blockIdx.x * 256 + threadIdx.x;
    int e = t >> 5;
    if (e >= E) return;
    int lane = t & 31;
    int s = src[e], d = dst[e];
    float nrm = dinv[s] * dinv[d];
    float4 v = *(const float4*)(HW + (size_t)s * DIM + lane * 4);
    float* o = out + (size_t)d * DIM + lane * 4;
    atomicAdd(o + 0, nrm * v.x);
    atomicAdd(o + 1, nrm * v.y);
    atomicAdd(o + 2, nrm * v.z);
    atomicAdd(o + 3, nrm * v.w);
}

// ---------------- out = relu(out + b) ----------------
__global__ __launch_bounds__(256) void k_bias_relu(float* __restrict__ out,
                                                   const float* __restrict__ b, int n) {
    int idx = blockIdx.x * 256 + threadIdx.x;   // over n*32 float4
    if (idx >= n * 32) return;
    int c4 = idx & 31;
    float4 bv = ((const float4*)b)[c4];
    float4 v = ((float4*)out)[idx];
    v.x = fmaxf(v.x + bv.x, 0.f);
    v.y = fmaxf(v.y + bv.y, 0.f);
    v.z = fmaxf(v.z + bv.z, 0.f);
    v.w = fmaxf(v.w + bv.w, 0.f);
    ((float4*)out)[idx] = v;
}

extern "C" void kernel_launch(void* const* d_in, const int* in_sizes, int n_in,
                              void* d_out, int out_size, void* d_ws, size_t ws_size,
                              hipStream_t stream) {
    const float* x  = (const float*)d_in[0];
    const int*   ei = (const int*)d_in[1];     // int64 in ref -> int32 from harness
    const float* Ws = (const float*)d_in[2];
    const float* bs = (const float*)d_in[3];

    const int N = in_sizes[0] / DIM;           // 100000
    const int E = in_sizes[1] / 2;             // 640000
    const int L = in_sizes[2] / (DIM * DIM);   // 3

    const int* src = ei;
    const int* dst = ei + E;

    float* out  = (float*)d_out;
    float* dinv = (float*)d_ws;                        // N floats (deg -> dinv in place)
    float* A    = dinv + ((N + 255) & ~255);           // N*128 floats scratch for H@W

    // degrees (include self-loop) -> dinv, once per launch
    k_init_deg <<<(N + 255) / 256, 256, 0, stream>>>(dinv, N);
    k_count_deg<<<(E + 255) / 256, 256, 0, stream>>>(dst, dinv, E);
    k_dinv     <<<(N + 255) / 256, 256, 0, stream>>>(dinv, N);

    const int nblk_rows = (N * 32 + 255) / 256;        // elementwise grids
    const float* h = x;
    for (int l = 0; l < L; ++l) {
        k_gemm    <<<(N + 15) / 16, 256, 0, stream>>>(h, Ws + (size_t)l * DIM * DIM, A, N);
        k_selfinit<<<nblk_rows, 256, 0, stream>>>(A, dinv, out, N);
        k_scatter <<<(E * 32 + 255) / 256, 256, 0, stream>>>(A, src, dst, dinv, out, E);
        k_bias_relu<<<nblk_rows, 256, 0, stream>>>(out, bs + (size_t)l * DIM, N);
        h = out;
    }
}

// Round 2
// 732.721 us; speedup vs baseline: 5.1590x; 5.1590x over previous
//
#include <hip/hip_runtime.h>

#define DIM 128

// ---------------- degree count (int) ----------------
__global__ __launch_bounds__(256) void k_count(const int* __restrict__ dst,
                                               int* __restrict__ cnt, int E) {
    int e = blockIdx.x * 256 + threadIdx.x;
    if (e < E) atomicAdd(&cnt[dst[e]], 1);
}

// dinv[i] = rsqrt(cnt[i] + 1)   (self-loop included, deg >= 1 always)
__global__ __launch_bounds__(256) void k_dinv(const int* __restrict__ cnt,
                                              float* __restrict__ dinv, int n) {
    int i = blockIdx.x * 256 + threadIdx.x;
    if (i < n) dinv[i] = rsqrtf((float)(cnt[i] + 1));
}

// ---------------- 3-kernel exclusive-ish scan (inclusive per element) ----------------
__global__ __launch_bounds__(256) void k_scan1(const int* __restrict__ cnt,
                                               int* __restrict__ incl,
                                               int* __restrict__ bsums, int n) {
    __shared__ int tmp[256];
    int i = blockIdx.x * 256 + threadIdx.x;
    int t = threadIdx.x;
    tmp[t] = (i < n) ? cnt[i] : 0;
    __syncthreads();
#pragma unroll
    for (int off = 1; off < 256; off <<= 1) {
        int v = (t >= off) ? tmp[t - off] : 0;
        __syncthreads();
        tmp[t] += v;
        __syncthreads();
    }
    if (i < n) incl[i] = tmp[t];
    if (t == 255) bsums[blockIdx.x] = tmp[255];
}

// single block: bsums -> exclusive scan of block sums (nb <= 512)
__global__ __launch_bounds__(512) void k_scan2(int* __restrict__ bsums, int nb) {
    __shared__ int tmp[512];
    int t = threadIdx.x;
    tmp[t] = (t < nb) ? bsums[t] : 0;
    __syncthreads();
#pragma unroll
    for (int off = 1; off < 512; off <<= 1) {
        int v = (t >= off) ? tmp[t - off] : 0;
        __syncthreads();
        tmp[t] += v;
        __syncthreads();
    }
    if (t < nb) bsums[t] = (t == 0) ? 0 : tmp[t - 1];
    }

__global__ __launch_bounds__(256) void k_scan3(int* __restrict__ incl,
                                               const int* __restrict__ bsums, int n) {
    int i = blockIdx.x * 256 + threadIdx.x;
    if (i < n) incl[i] += bsums[blockIdx.x];
}

// ---------------- CSR fill: bucket src by dst, decrementing incl -> becomes rowptr ----------------
__global__ __launch_bounds__(256) void k_fill(const int* __restrict__ src,
                                              const int* __restrict__ dst,
                                              int* __restrict__ incl,
                                              int* __restrict__ srcs, int E) {
    int e = blockIdx.x * 256 + threadIdx.x;
    if (e >= E) return;
    int p = atomicSub(&incl[dst[e]], 1) - 1;
    srcs[p] = src[e];
}

// ---------------- HW = H @ W ----------------
__global__ __launch_bounds__(256) void k_gemm(const float* __restrict__ H,
                                              const float* __restrict__ W,
                                              float* __restrict__ HW, int n) {
    __shared__ float sW[DIM * DIM];
    __shared__ float sH[16 * 132];
    int tid = threadIdx.x;

    const float4* W4 = (const float4*)W;
    float4* sW4 = (float4*)sW;
#pragma unroll
    for (int i = 0; i < 16; ++i) sW4[tid + i * 256] = W4[tid + i * 256];

    int row0 = blockIdx.x * 16;
#pragma unroll
    for (int i = 0; i < 2; ++i) {
        int idx = tid + i * 256;
        int r = idx >> 5;
        int c = idx & 31;
        int rg = row0 + r;
        float4 v = make_float4(0.f, 0.f, 0.f, 0.f);
        if (rg < n) v = ((const float4*)(H + (size_t)rg * DIM))[c];
        *(float4*)(sH + r * 132 + c * 4) = v;
    }
    __syncthreads();

    int rl = tid >> 4;
    int jg = tid & 15;
    float acc[8] = {0, 0, 0, 0, 0, 0, 0, 0};
    const float* hrow = sH + rl * 132;
#pragma unroll 4
    for (int k = 0; k < DIM; ++k) {
        float hv = hrow[k];
        const float* w = sW + k * DIM + jg * 8;
        float4 w0 = *(const float4*)(w);
        float4 w1 = *(const float4*)(w + 4);
        acc[0] += hv * w0.x; acc[1] += hv * w0.y;
        acc[2] += hv * w0.z; acc[3] += hv * w0.w;
        acc[4] += hv * w1.x; acc[5] += hv * w1.y;
        acc[6] += hv * w1.z; acc[7] += hv * w1.w;
    }
    int rg = row0 + rl;
    if (rg < n) {
        float* o = HW + (size_t)rg * DIM + jg * 8;
        *(float4*)o       = make_float4(acc[0], acc[1], acc[2], acc[3]);
        *(float4*)(o + 4) = make_float4(acc[4], acc[5], acc[6], acc[7]);
    }
}

// ---------------- CSR aggregate + self-loop + bias + relu, one wave per node ----------------
__global__ __launch_bounds__(256) void k_aggregate(const float* __restrict__ A,
                                                   const int* __restrict__ srcs,
                                                   const int* __restrict__ rowptr,
                                                   const float* __restrict__ dinv,
                                                   const float* __restrict__ bias,
                                                   float* __restrict__ out, int n, int E) {
    int node = blockIdx.x * 4 + (threadIdx.x >> 6);
    if (node >= n) return;
    int lane = threadIdx.x & 63;
    int start = rowptr[node];
    int end = (node + 1 < n) ? rowptr[node + 1] : E;
    float di = dinv[node];

    float2 v = ((const float2*)(A + (size_t)node * DIM))[lane];
    float2 acc;
    acc.x = di * di * v.x;
    acc.y = di * di * v.y;

    for (int p = start; p < end; ++p) {
        int s = srcs[p];
        float w = di * dinv[s];
        float2 m = ((const float2*)(A + (size_t)s * DIM))[lane];
        acc.x += w * m.x;
        acc.y += w * m.y;
    }
    float2 b = ((const float2*)bias)[lane];
    acc.x = fmaxf(acc.x + b.x, 0.f);
    acc.y = fmaxf(acc.y + b.y, 0.f);
    ((float2*)(out + (size_t)node * DIM))[lane] = acc;
}

extern "C" void kernel_launch(void* const* d_in, const int* in_sizes, int n_in,
                              void* d_out, int out_size, void* d_ws, size_t ws_size,
                              hipStream_t stream) {
    const float* x  = (const float*)d_in[0];
    const int*   ei = (const int*)d_in[1];
    const float* Ws = (const float*)d_in[2];
    const float* bs = (const float*)d_in[3];

    const int N = in_sizes[0] / DIM;           // 100000
    const int E = in_sizes[1] / 2;             // 640000
    const int L = in_sizes[2] / (DIM * DIM);   // 3

    const int* src = ei;
    const int* dst = ei + E;

    float* out = (float*)d_out;

    // workspace carve (4-byte units)
    char* ws = (char*)d_ws;
    float* A     = (float*)ws;                 ws += (size_t)N * DIM * 4;   // 51.2 MB
    float* dinv  = (float*)ws;                 ws += (size_t)N * 4;
    int*   cnt   = (int*)ws;                   ws += (size_t)N * 4;
    int*   incl  = (int*)ws;                   ws += (size_t)N * 4;        // -> rowptr
    int*   srcs  = (int*)ws;                   ws += (size_t)E * 4;        // 2.56 MB
    int*   bsums = (int*)ws;                   ws += 512 * 4;

    const int nbN = (N + 255) / 256;           // 391 (<512, fits k_scan2)
    const int nbE = (E + 255) / 256;

    // ---- CSR build + dinv (once per launch) ----
    hipMemsetAsync(cnt, 0, (size_t)N * 4, stream);
    k_count<<<nbE, 256, 0, stream>>>(dst, cnt, E);
    k_dinv <<<nbN, 256, 0, stream>>>(cnt, dinv, N);
    k_scan1<<<nbN, 256, 0, stream>>>(cnt, incl, bsums, N);
    k_scan2<<<1, 512, 0, stream>>>(bsums, nbN);
    k_scan3<<<nbN, 256, 0, stream>>>(incl, bsums, N);
    k_fill <<<nbE, 256, 0, stream>>>(src, dst, incl, srcs, E);
    // incl now holds exclusive row starts (rowptr)

    // ---- layers ----
    const float* h = x;
    for (int l = 0; l < L; ++l) {
        k_gemm<<<(N + 15) / 16, 256, 0, stream>>>(h, Ws + (size_t)l * DIM * DIM, A, N);
        k_aggregate<<<(N + 3) / 4, 256, 0, stream>>>(A, srcs, incl, dinv,
                                                     bs + (size_t)l * DIM, out, N, E);
        h = out;
    }
}

// Round 3
// 490.400 us; speedup vs baseline: 7.7082x; 1.4941x over previous
//
#include <hip/hip_runtime.h>

#define DIM 128
#define KC 32
#define SHS 36   // sHT row stride (floats): 16B-aligned, broadcast-friendly

// ---------------- degree count (int) ----------------
__global__ __launch_bounds__(256) void k_count(const int* __restrict__ dst,
                                               int* __restrict__ cnt, int E) {
    int e = blockIdx.x * 256 + threadIdx.x;
    if (e < E) atomicAdd(&cnt[dst[e]], 1);
}

// dinv[i] = rsqrt(cnt[i] + 1)   (self-loop included, deg >= 1 always)
__global__ __launch_bounds__(256) void k_dinv(const int* __restrict__ cnt,
                                              float* __restrict__ dinv, int n) {
    int i = blockIdx.x * 256 + threadIdx.x;
    if (i < n) dinv[i] = rsqrtf((float)(cnt[i] + 1));
}

// ---------------- scan (3-kernel) ----------------
__global__ __launch_bounds__(256) void k_scan1(const int* __restrict__ cnt,
                                               int* __restrict__ incl,
                                               int* __restrict__ bsums, int n) {
    __shared__ int tmp[256];
    int i = blockIdx.x * 256 + threadIdx.x;
    int t = threadIdx.x;
    tmp[t] = (i < n) ? cnt[i] : 0;
    __syncthreads();
#pragma unroll
    for (int off = 1; off < 256; off <<= 1) {
        int v = (t >= off) ? tmp[t - off] : 0;
        __syncthreads();
        tmp[t] += v;
        __syncthreads();
    }
    if (i < n) incl[i] = tmp[t];
    if (t == 255) bsums[blockIdx.x] = tmp[255];
}

__global__ __launch_bounds__(512) void k_scan2(int* __restrict__ bsums, int nb) {
    __shared__ int tmp[512];
    int t = threadIdx.x;
    tmp[t] = (t < nb) ? bsums[t] : 0;
    __syncthreads();
#pragma unroll
    for (int off = 1; off < 512; off <<= 1) {
        int v = (t >= off) ? tmp[t - off] : 0;
        __syncthreads();
        tmp[t] += v;
        __syncthreads();
    }
    if (t < nb) bsums[t] = (t == 0) ? 0 : tmp[t - 1];
}

__global__ __launch_bounds__(256) void k_scan3(int* __restrict__ incl,
                                               const int* __restrict__ bsums, int n) {
    int i = blockIdx.x * 256 + threadIdx.x;
    if (i < n) incl[i] += bsums[blockIdx.x];
}

// ---------------- CSR fill ----------------
__global__ __launch_bounds__(256) void k_fill(const int* __restrict__ src,
                                              const int* __restrict__ dst,
                                              int* __restrict__ incl,
                                              int* __restrict__ srcs, int E) {
    int e = blockIdx.x * 256 + threadIdx.x;
    if (e >= E) return;
    int p = atomicSub(&incl[dst[e]], 1) - 1;
    srcs[p] = src[e];
}

// ---------------- A' = dinv[r] * (H[r] @ W) ----------------
// 256 thr, 32 rows/block. thread (cg 0..31, wg 0..7): cols cg*4..+3, rows wg*4..+3.
// sW read: 32 consecutive b128 per wave -> conflict-free. sHT read: broadcast -> free.
__global__ __launch_bounds__(256) void k_gemm(const float* __restrict__ H,
                                              const float* __restrict__ W,
                                              const float* __restrict__ dinv,
                                              float* __restrict__ HW, int n) {
    __shared__ float sW[KC * DIM];      // 16 KB
    __shared__ float sHT[KC * SHS];     // 4.6 KB, sHT[k][row]
    int tid = threadIdx.x;
    int row0 = blockIdx.x * 32;
    int cg = tid & 31;
    int wg = tid >> 5;
    int srow = tid >> 3;                // 0..31 (staging row)
    int skg  = tid & 7;                 // 0..7  (staging k-group)
    bool rv = (row0 + srow) < n;
    const float* Hrow = H + (size_t)(row0 + srow) * DIM;

    float acc[4][4];
#pragma unroll
    for (int r = 0; r < 4; ++r)
#pragma unroll
        for (int c = 0; c < 4; ++c) acc[r][c] = 0.f;

    for (int k0 = 0; k0 < DIM; k0 += KC) {
        // stage W chunk [KC][128], coalesced, linear LDS
        const float4* Wg = (const float4*)(W + (size_t)k0 * DIM);
        float4* sW4 = (float4*)sW;
#pragma unroll
        for (int i = 0; i < 4; ++i) sW4[tid + i * 256] = Wg[tid + i * 256];
        // stage H chunk transposed: sHT[k][row]
        float4 v = make_float4(0.f, 0.f, 0.f, 0.f);
        if (rv) v = *(const float4*)(Hrow + k0 + skg * 4);
        sHT[(skg * 4 + 0) * SHS + srow] = v.x;
        sHT[(skg * 4 + 1) * SHS + srow] = v.y;
        sHT[(skg * 4 + 2) * SHS + srow] = v.z;
        sHT[(skg * 4 + 3) * SHS + srow] = v.w;
        __syncthreads();

#pragma unroll
        for (int kk = 0; kk < KC; ++kk) {
            float4 hv = *(const float4*)(sHT + kk * SHS + wg * 4);
            float4 wv = *(const float4*)(sW + kk * DIM + cg * 4);
            acc[0][0] += hv.x * wv.x; acc[0][1] += hv.x * wv.y;
            acc[0][2] += hv.x * wv.z; acc[0][3] += hv.x * wv.w;
            acc[1][0] += hv.y * wv.x; acc[1][1] += hv.y * wv.y;
            acc[1][2] += hv.y * wv.z; acc[1][3] += hv.y * wv.w;
            acc[2][0] += hv.z * wv.x; acc[2][1] += hv.z * wv.y;
            acc[2][2] += hv.z * wv.z; acc[2][3] += hv.z * wv.w;
            acc[3][0] += hv.w * wv.x; acc[3][1] += hv.w * wv.y;
            acc[3][2] += hv.w * wv.z; acc[3][3] += hv.w * wv.w;
        }
        __syncthreads();
    }

#pragma unroll
    for (int r = 0; r < 4; ++r) {
        int rg = row0 + wg * 4 + r;
        if (rg < n) {
            float dv = dinv[rg];
            float4 o = make_float4(dv * acc[r][0], dv * acc[r][1],
                                   dv * acc[r][2], dv * acc[r][3]);
            *(float4*)(HW + (size_t)rg * DIM + cg * 4) = o;
        }
    }
}

// ---------------- out[d] = relu(dinv[d]*(A'[d] + sum A'[src]) + b) ----------------
__global__ __launch_bounds__(256) void k_aggregate(const float* __restrict__ A,
                                                   const int* __restrict__ srcs,
                                                   const int* __restrict__ rowptr,
                                                   const float* __restrict__ dinv,
                                                   const float* __restrict__ bias,
                                                   float* __restrict__ out, int n, int E) {
    int node = blockIdx.x * 4 + (threadIdx.x >> 6);
    if (node >= n) return;
    int lane = threadIdx.x & 63;
    int start = rowptr[node];
    int end = (node + 1 < n) ? rowptr[node + 1] : E;

    float2 acc = ((const float2*)(A + (size_t)node * DIM))[lane];

    int p = start;
    for (; p + 2 <= end; p += 2) {
        int s0 = srcs[p];
        int s1 = srcs[p + 1];
        float2 m0 = ((const float2*)(A + (size_t)s0 * DIM))[lane];
        float2 m1 = ((const float2*)(A + (size_t)s1 * DIM))[lane];
        acc.x += m0.x + m1.x;
        acc.y += m0.y + m1.y;
    }
    if (p < end) {
        int s = srcs[p];
        float2 m = ((const float2*)(A + (size_t)s * DIM))[lane];
        acc.x += m.x;
        acc.y += m.y;
    }

    float di = dinv[node];
    float2 b = ((const float2*)bias)[lane];
    float2 o;
    o.x = fmaxf(di * acc.x + b.x, 0.f);
    o.y = fmaxf(di * acc.y + b.y, 0.f);
    ((float2*)(out + (size_t)node * DIM))[lane] = o;
}

extern "C" void kernel_launch(void* const* d_in, const int* in_sizes, int n_in,
                              void* d_out, int out_size, void* d_ws, size_t ws_size,
                              hipStream_t stream) {
    const float* x  = (const float*)d_in[0];
    const int*   ei = (const int*)d_in[1];
    const float* Ws = (const float*)d_in[2];
    const float* bs = (const float*)d_in[3];

    const int N = in_sizes[0] / DIM;           // 100000
    const int E = in_sizes[1] / 2;             // 640000
    const int L = in_sizes[2] / (DIM * DIM);   // 3

    const int* src = ei;
    const int* dst = ei + E;

    float* out = (float*)d_out;

    char* ws = (char*)d_ws;
    float* A     = (float*)ws;                 ws += (size_t)N * DIM * 4;
    float* dinv  = (float*)ws;                 ws += (size_t)N * 4;
    int*   cnt   = (int*)ws;                   ws += (size_t)N * 4;
    int*   incl  = (int*)ws;                   ws += (size_t)N * 4;
    int*   srcs  = (int*)ws;                   ws += (size_t)E * 4;
    int*   bsums = (int*)ws;                   ws += 512 * 4;

    const int nbN = (N + 255) / 256;           // 391 (< 512)
    const int nbE = (E + 255) / 256;

    hipMemsetAsync(cnt, 0, (size_t)N * 4, stream);
    k_count<<<nbE, 256, 0, stream>>>(dst, cnt, E);
    k_dinv <<<nbN, 256, 0, stream>>>(cnt, dinv, N);
    k_scan1<<<nbN, 256, 0, stream>>>(cnt, incl, bsums, N);
    k_scan2<<<1, 512, 0, stream>>>(bsums, nbN);
    k_scan3<<<nbN, 256, 0, stream>>>(incl, bsums, N);
    k_fill <<<nbE, 256, 0, stream>>>(src, dst, incl, srcs, E);

    const float* h = x;
    for (int l = 0; l < L; ++l) {
        k_gemm<<<(N + 31) / 32, 256, 0, stream>>>(h, Ws + (size_t)l * DIM * DIM, dinv, A, N);
        k_aggregate<<<(N + 3) / 4, 256, 0, stream>>>(A, srcs, incl, dinv,
                                                     bs + (size_t)l * DIM, out, N, E);
        h = out;
    }
}

// Round 4
// 455.501 us; speedup vs baseline: 8.2988x; 1.0766x over previous
//
#include <hip/hip_runtime.h>

#define DIM 128
#define KC 32
#define SHS 36   // sHT row stride (floats)

typedef unsigned int uint32;

// pack two fp32 -> 2x bf16 in one uint (round-half-up)
__device__ __forceinline__ uint32 packbf2(float lo, float hi) {
    uint32 a = __float_as_uint(lo);
    uint32 b = __float_as_uint(hi);
    return ((a + 0x8000u) >> 16) | ((b + 0x8000u) & 0xffff0000u);
}
__device__ __forceinline__ float bflo(uint32 u) { return __uint_as_float(u << 16); }
__device__ __forceinline__ float bfhi(uint32 u) { return __uint_as_float(u & 0xffff0000u); }

// ---------------- degree count ----------------
__global__ __launch_bounds__(256) void k_count(const int* __restrict__ dst,
                                               int* __restrict__ cnt, int E) {
    int e = blockIdx.x * 256 + threadIdx.x;
    if (e < E) atomicAdd(&cnt[dst[e]], 1);
}

__global__ __launch_bounds__(256) void k_dinv(const int* __restrict__ cnt,
                                              float* __restrict__ dinv, int n) {
    int i = blockIdx.x * 256 + threadIdx.x;
    if (i < n) dinv[i] = rsqrtf((float)(cnt[i] + 1));
}

// ---------------- scan ----------------
__global__ __launch_bounds__(256) void k_scan1(const int* __restrict__ cnt,
                                               int* __restrict__ incl,
                                               int* __restrict__ bsums, int n) {
    __shared__ int tmp[256];
    int i = blockIdx.x * 256 + threadIdx.x;
    int t = threadIdx.x;
    tmp[t] = (i < n) ? cnt[i] : 0;
    __syncthreads();
#pragma unroll
    for (int off = 1; off < 256; off <<= 1) {
        int v = (t >= off) ? tmp[t - off] : 0;
        __syncthreads();
        tmp[t] += v;
        __syncthreads();
    }
    if (i < n) incl[i] = tmp[t];
    if (t == 255) bsums[blockIdx.x] = tmp[255];
}

__global__ __launch_bounds__(512) void k_scan2(int* __restrict__ bsums, int nb) {
    __shared__ int tmp[512];
    int t = threadIdx.x;
    tmp[t] = (t < nb) ? bsums[t] : 0;
    __syncthreads();
#pragma unroll
    for (int off = 1; off < 512; off <<= 1) {
        int v = (t >= off) ? tmp[t - off] : 0;
        __syncthreads();
        tmp[t] += v;
        __syncthreads();
    }
    if (t < nb) bsums[t] = (t == 0) ? 0 : tmp[t - 1];
}

__global__ __launch_bounds__(256) void k_scan3(int* __restrict__ incl,
                                               const int* __restrict__ bsums, int n) {
    int i = blockIdx.x * 256 + threadIdx.x;
    if (i < n) incl[i] += bsums[blockIdx.x];
}

// ---------------- CSR fill ----------------
__global__ __launch_bounds__(256) void k_fill(const int* __restrict__ src,
                                              const int* __restrict__ dst,
                                              int* __restrict__ incl,
                                              int* __restrict__ srcs, int E) {
    int e = blockIdx.x * 256 + threadIdx.x;
    if (e >= E) return;
    int p = atomicSub(&incl[dst[e]], 1) - 1;
    srcs[p] = src[e];
}

// ---------------- A'(bf16) = dinv[r] * (H[r] @ W) ----------------
__global__ __launch_bounds__(256) void k_gemm(const float* __restrict__ H,
                                              const float* __restrict__ W,
                                              const float* __restrict__ dinv,
                                              uint32* __restrict__ HWb, int n) {
    __shared__ float sW[KC * DIM];      // 16 KB
    __shared__ float sHT[KC * SHS];
    int tid = threadIdx.x;
    int row0 = blockIdx.x * 32;
    int cg = tid & 31;
    int wg = tid >> 5;
    int srow = tid >> 3;
    int skg  = tid & 7;
    bool rv = (row0 + srow) < n;
    const float* Hrow = H + (size_t)(row0 + srow) * DIM;

    float acc[4][4];
#pragma unroll
    for (int r = 0; r < 4; ++r)
#pragma unroll
        for (int c = 0; c < 4; ++c) acc[r][c] = 0.f;

    for (int k0 = 0; k0 < DIM; k0 += KC) {
        const float4* Wg = (const float4*)(W + (size_t)k0 * DIM);
        float4* sW4 = (float4*)sW;
#pragma unroll
        for (int i = 0; i < 4; ++i) sW4[tid + i * 256] = Wg[tid + i * 256];
        float4 v = make_float4(0.f, 0.f, 0.f, 0.f);
        if (rv) v = *(const float4*)(Hrow + k0 + skg * 4);
        sHT[(skg * 4 + 0) * SHS + srow] = v.x;
        sHT[(skg * 4 + 1) * SHS + srow] = v.y;
        sHT[(skg * 4 + 2) * SHS + srow] = v.z;
        sHT[(skg * 4 + 3) * SHS + srow] = v.w;
        __syncthreads();

#pragma unroll
        for (int kk = 0; kk < KC; ++kk) {
            float4 hv = *(const float4*)(sHT + kk * SHS + wg * 4);
            float4 wv = *(const float4*)(sW + kk * DIM + cg * 4);
            acc[0][0] += hv.x * wv.x; acc[0][1] += hv.x * wv.y;
            acc[0][2] += hv.x * wv.z; acc[0][3] += hv.x * wv.w;
            acc[1][0] += hv.y * wv.x; acc[1][1] += hv.y * wv.y;
            acc[1][2] += hv.y * wv.z; acc[1][3] += hv.y * wv.w;
            acc[2][0] += hv.z * wv.x; acc[2][1] += hv.z * wv.y;
            acc[2][2] += hv.z * wv.z; acc[2][3] += hv.z * wv.w;
            acc[3][0] += hv.w * wv.x; acc[3][1] += hv.w * wv.y;
            acc[3][2] += hv.w * wv.z; acc[3][3] += hv.w * wv.w;
        }
        __syncthreads();
    }

#pragma unroll
    for (int r = 0; r < 4; ++r) {
        int rg = row0 + wg * 4 + r;
        if (rg < n) {
            float dv = dinv[rg];
            uint32 p0 = packbf2(dv * acc[r][0], dv * acc[r][1]);
            uint32 p1 = packbf2(dv * acc[r][2], dv * acc[r][3]);
            *(uint2*)(HWb + (size_t)rg * 64 + cg * 2) = make_uint2(p0, p1);
        }
    }
}

// ---------------- out[d] = relu(dinv[d]*(A'[d] + sum A'[src]) + b) ----------------
// one node per 64-lane wave; lane owns cols {2l, 2l+1} (one packed uint per row)
__global__ __launch_bounds__(256) void k_aggregate(const uint32* __restrict__ A,
                                                   const int* __restrict__ srcs,
                                                   const int* __restrict__ rowptr,
                                                   const float* __restrict__ dinv,
                                                   const float* __restrict__ bias,
                                                   float* __restrict__ out, int n, int E) {
    int node = blockIdx.x * 4 + (threadIdx.x >> 6);
    if (node >= n) return;
    int lane = threadIdx.x & 63;
    int start = rowptr[node];
    int end = (node + 1 < n) ? rowptr[node + 1] : E;

    uint32 us = A[(size_t)node * 64 + lane];
    float ax = bflo(us), ay = bfhi(us);

    int p = start;
    for (; p + 4 <= end; p += 4) {
        int s0 = srcs[p + 0];
        int s1 = srcs[p + 1];
        int s2 = srcs[p + 2];
        int s3 = srcs[p + 3];
        uint32 u0 = A[(size_t)s0 * 64 + lane];
        uint32 u1 = A[(size_t)s1 * 64 + lane];
        uint32 u2 = A[(size_t)s2 * 64 + lane];
        uint32 u3 = A[(size_t)s3 * 64 + lane];
        ax += bflo(u0) + bflo(u1) + bflo(u2) + bflo(u3);
        ay += bfhi(u0) + bfhi(u1) + bfhi(u2) + bfhi(u3);
    }
    for (; p < end; ++p) {
        uint32 u = A[(size_t)srcs[p] * 64 + lane];
        ax += bflo(u);
        ay += bfhi(u);
    }

    float di = dinv[node];
    float2 b = ((const float2*)bias)[lane];
    float2 o;
    o.x = fmaxf(di * ax + b.x, 0.f);
    o.y = fmaxf(di * ay + b.y, 0.f);
    ((float2*)(out + (size_t)node * DIM))[lane] = o;
}

extern "C" void kernel_launch(void* const* d_in, const int* in_sizes, int n_in,
                              void* d_out, int out_size, void* d_ws, size_t ws_size,
                              hipStream_t stream) {
    const float* x  = (const float*)d_in[0];
    const int*   ei = (const int*)d_in[1];
    const float* Ws = (const float*)d_in[2];
    const float* bs = (const float*)d_in[3];

    const int N = in_sizes[0] / DIM;           // 100000
    const int E = in_sizes[1] / 2;             // 640000
    const int L = in_sizes[2] / (DIM * DIM);   // 3

    const int* src = ei;
    const int* dst = ei + E;

    float* out = (float*)d_out;

    char* ws = (char*)d_ws;
    uint32* A    = (uint32*)ws;                ws += (size_t)N * 64 * 4;   // bf16 A', 25.6 MB
    float* dinv  = (float*)ws;                 ws += (size_t)N * 4;
    int*   cnt   = (int*)ws;                   ws += (size_t)N * 4;
    int*   incl  = (int*)ws;                   ws += (size_t)N * 4;
    int*   srcs  = (int*)ws;                   ws += (size_t)E * 4;
    int*   bsums = (int*)ws;                   ws += 512 * 4;

    const int nbN = (N + 255) / 256;           // 391 (< 512)
    const int nbE = (E + 255) / 256;

    hipMemsetAsync(cnt, 0, (size_t)N * 4, stream);
    k_count<<<nbE, 256, 0, stream>>>(dst, cnt, E);
    k_dinv <<<nbN, 256, 0, stream>>>(cnt, dinv, N);
    k_scan1<<<nbN, 256, 0, stream>>>(cnt, incl, bsums, N);
    k_scan2<<<1, 512, 0, stream>>>(bsums, nbN);
    k_scan3<<<nbN, 256, 0, stream>>>(incl, bsums, N);
    k_fill <<<nbE, 256, 0, stream>>>(src, dst, incl, srcs, E);

    const float* h = x;
    for (int l = 0; l < L; ++l) {
        k_gemm<<<(N + 31) / 32, 256, 0, stream>>>(h, Ws + (size_t)l * DIM * DIM, dinv, A, N);
        k_aggregate<<<(N + 3) / 4, 256, 0, stream>>>(A, srcs, incl, dinv,
                                                     bs + (size_t)l * DIM, out, N, E);
        h = out;
    }
}

// Round 5
// 397.753 us; speedup vs baseline: 9.5036x; 1.1452x over previous
//
#include <hip/hip_runtime.h>

#define DIM 128

typedef unsigned int uint32;
typedef short bf16x8 __attribute__((ext_vector_type(8)));
typedef float f32x4 __attribute__((ext_vector_type(4)));

// fp32 -> bf16 bits (round-half-up on magnitude)
__device__ __forceinline__ unsigned short f2b(float f) {
    return (unsigned short)((__float_as_uint(f) + 0x8000u) >> 16);
}
__device__ __forceinline__ float bflo(uint32 u) { return __uint_as_float(u << 16); }
__device__ __forceinline__ float bfhi(uint32 u) { return __uint_as_float(u & 0xffff0000u); }

// ---------------- degree count ----------------
__global__ __launch_bounds__(256) void k_count(const int* __restrict__ dst,
                                               int* __restrict__ cnt, int E) {
    int e = blockIdx.x * 256 + threadIdx.x;
    if (e < E) atomicAdd(&cnt[dst[e]], 1);
}

__global__ __launch_bounds__(256) void k_dinv(const int* __restrict__ cnt,
                                              float* __restrict__ dinv, int n) {
    int i = blockIdx.x * 256 + threadIdx.x;
    if (i < n) dinv[i] = rsqrtf((float)(cnt[i] + 1));
}

// ---------------- scan ----------------
__global__ __launch_bounds__(256) void k_scan1(const int* __restrict__ cnt,
                                               int* __restrict__ incl,
                                               int* __restrict__ bsums, int n) {
    __shared__ int tmp[256];
    int i = blockIdx.x * 256 + threadIdx.x;
    int t = threadIdx.x;
    tmp[t] = (i < n) ? cnt[i] : 0;
    __syncthreads();
#pragma unroll
    for (int off = 1; off < 256; off <<= 1) {
        int v = (t >= off) ? tmp[t - off] : 0;
        __syncthreads();
        tmp[t] += v;
        __syncthreads();
    }
    if (i < n) incl[i] = tmp[t];
    if (t == 255) bsums[blockIdx.x] = tmp[255];
}

__global__ __launch_bounds__(512) void k_scan2(int* __restrict__ bsums, int nb) {
    __shared__ int tmp[512];
    int t = threadIdx.x;
    tmp[t] = (t < nb) ? bsums[t] : 0;
    __syncthreads();
#pragma unroll
    for (int off = 1; off < 512; off <<= 1) {
        int v = (t >= off) ? tmp[t - off] : 0;
        __syncthreads();
        tmp[t] += v;
        __syncthreads();
    }
    if (t < nb) bsums[t] = (t == 0) ? 0 : tmp[t - 1];
}

__global__ __launch_bounds__(256) void k_scan3(int* __restrict__ incl,
                                               const int* __restrict__ bsums, int n) {
    int i = blockIdx.x * 256 + threadIdx.x;
    if (i < n) incl[i] += bsums[blockIdx.x];
}

// ---------------- CSR fill ----------------
__global__ __launch_bounds__(256) void k_fill(const int* __restrict__ src,
                                              const int* __restrict__ dst,
                                              int* __restrict__ incl,
                                              int* __restrict__ srcs, int E) {
    int e = blockIdx.x * 256 + threadIdx.x;
    if (e >= E) return;
    int p = atomicSub(&incl[dst[e]], 1) - 1;
    srcs[p] = src[e];
}

// ---------------- W -> per-lane bf16 B-fragments ----------------
// frag f = (w*2 + cs)*4 + ks  (w: wave/32-col strip, cs: 16-col subtile, ks: K-step of 32)
// Wb[((f*64 + l)*8 + j] = bf16(W[k][n]),  n = w*32+cs*16+(l&15),
// k = ks*32 + ((j<4) ? (l>>4)*4+j : 16+(l>>4)*4+(j-4))
// (k-slot map only needs to MATCH the A-side fill; any common permutation sums identically)
__global__ __launch_bounds__(256) void k_prepW(const float* __restrict__ Ws,
                                               short* __restrict__ Wb, int total) {
    int t = blockIdx.x * 256 + threadIdx.x;
    if (t >= total) return;
    int layer = t >> 14;
    int idx = t & 16383;
    int j = idx & 7;
    int l = (idx >> 3) & 63;
    int f = idx >> 9;          // 0..31
    int ks = f & 3;
    int cs = (f >> 2) & 1;
    int w = f >> 3;
    int nn = w * 32 + cs * 16 + (l & 15);
    int kk = ks * 32 + ((j < 4) ? ((l >> 4) * 4 + j) : (16 + (l >> 4) * 4 + (j - 4)));
    Wb[t] = (short)f2b(Ws[(size_t)layer * DIM * DIM + kk * DIM + nn]);
}

// ---------------- A'(bf16) = dinv[r] * (H[r] @ W), MFMA ----------------
// block = 32 rows x 128 cols, 4 waves; wave w owns cols w*32..w*32+31.
// B-frags register-resident (8 x 16B coalesced loads), A from fp32 H, no LDS.
__global__ __launch_bounds__(256) void k_gemm_mfma(const float* __restrict__ H,
                                                   const short* __restrict__ Wb,
                                                   const float* __restrict__ dinv,
                                                   unsigned short* __restrict__ Ab,
                                                   int n) {
    int tid = threadIdx.x;
    int w = tid >> 6;
    int l = tid & 63;
    int lr = l & 15;      // row/col within 16-subtile
    int lg = l >> 4;      // k-group
    int row0 = blockIdx.x * 32;

    const bf16x8* wb = (const bf16x8*)Wb;
    bf16x8 bfrag[2][4];
#pragma unroll
    for (int cs = 0; cs < 2; ++cs)
#pragma unroll
        for (int ks = 0; ks < 4; ++ks)
            bfrag[cs][ks] = wb[((w * 2 + cs) * 4 + ks) * 64 + l];

    f32x4 acc[2][2];
#pragma unroll
    for (int rs = 0; rs < 2; ++rs)
#pragma unroll
        for (int cs = 0; cs < 2; ++cs) acc[rs][cs] = (f32x4){0.f, 0.f, 0.f, 0.f};

    int r0 = row0 + lr;
    int r1 = row0 + 16 + lr;
    bool ok0 = r0 < n, ok1 = r1 < n;
    const float* h0 = H + (size_t)r0 * DIM + lg * 4;
    const float* h1 = H + (size_t)r1 * DIM + lg * 4;

#pragma unroll
    for (int ks = 0; ks < 4; ++ks) {
        float4 xa = ok0 ? *(const float4*)(h0 + ks * 32)      : make_float4(0, 0, 0, 0);
        float4 xb = ok0 ? *(const float4*)(h0 + ks * 32 + 16) : make_float4(0, 0, 0, 0);
        float4 ya = ok1 ? *(const float4*)(h1 + ks * 32)      : make_float4(0, 0, 0, 0);
        float4 yb = ok1 ? *(const float4*)(h1 + ks * 32 + 16) : make_float4(0, 0, 0, 0);
        bf16x8 a0, a1;
        a0[0] = (short)f2b(xa.x); a0[1] = (short)f2b(xa.y);
        a0[2] = (short)f2b(xa.z); a0[3] = (short)f2b(xa.w);
        a0[4] = (short)f2b(xb.x); a0[5] = (short)f2b(xb.y);
        a0[6] = (short)f2b(xb.z); a0[7] = (short)f2b(xb.w);
        a1[0] = (short)f2b(ya.x); a1[1] = (short)f2b(ya.y);
        a1[2] = (short)f2b(ya.z); a1[3] = (short)f2b(ya.w);
        a1[4] = (short)f2b(yb.x); a1[5] = (short)f2b(yb.y);
        a1[6] = (short)f2b(yb.z); a1[7] = (short)f2b(yb.w);
#pragma unroll
        for (int cs = 0; cs < 2; ++cs) {
            acc[0][cs] = __builtin_amdgcn_mfma_f32_16x16x32_bf16(a0, bfrag[cs][ks], acc[0][cs], 0, 0, 0);
            acc[1][cs] = __builtin_amdgcn_mfma_f32_16x16x32_bf16(a1, bfrag[cs][ks], acc[1][cs], 0, 0, 0);
        }
    }

    // C/D layout (m89-verified): col = l&15, row = (l>>4)*4 + reg
#pragma unroll
    for (int rs = 0; rs < 2; ++rs)
#pragma unroll
        for (int r = 0; r < 4; ++r) {
            int grow = row0 + rs * 16 + lg * 4 + r;
            if (grow < n) {
                float dv = dinv[grow];
#pragma unroll
                for (int cs = 0; cs < 2; ++cs)
                    Ab[(size_t)grow * DIM + w * 32 + cs * 16 + lr] =
                        f2b(dv * acc[rs][cs][r]);
            }
        }
}

// ---------------- out[d] = relu(dinv[d]*(A'[d] + sum A'[src]) + b) ----------------
__global__ __launch_bounds__(256) void k_aggregate(const uint32* __restrict__ A,
                                                   const int* __restrict__ srcs,
                                                   const int* __restrict__ rowptr,
                                                   const float* __restrict__ dinv,
                                                   const float* __restrict__ bias,
                                                   float* __restrict__ out, int n, int E) {
    int node = blockIdx.x * 4 + (threadIdx.x >> 6);
    if (node >= n) return;
    int lane = threadIdx.x & 63;
    int start = rowptr[node];
    int end = (node + 1 < n) ? rowptr[node + 1] : E;

    uint32 us = A[(size_t)node * 64 + lane];
    float ax = bflo(us), ay = bfhi(us);

    int p = start;
    for (; p + 4 <= end; p += 4) {
        int s0 = srcs[p + 0];
        int s1 = srcs[p + 1];
        int s2 = srcs[p + 2];
        int s3 = srcs[p + 3];
        uint32 u0 = A[(size_t)s0 * 64 + lane];
        uint32 u1 = A[(size_t)s1 * 64 + lane];
        uint32 u2 = A[(size_t)s2 * 64 + lane];
        uint32 u3 = A[(size_t)s3 * 64 + lane];
        ax += bflo(u0) + bflo(u1) + bflo(u2) + bflo(u3);
        ay += bfhi(u0) + bfhi(u1) + bfhi(u2) + bfhi(u3);
    }
    for (; p < end; ++p) {
        uint32 u = A[(size_t)srcs[p] * 64 + lane];
        ax += bflo(u);
        ay += bfhi(u);
    }

    float di = dinv[node];
    float2 b = ((const float2*)bias)[lane];
    float2 o;
    o.x = fmaxf(di * ax + b.x, 0.f);
    o.y = fmaxf(di * ay + b.y, 0.f);
    ((float2*)(out + (size_t)node * DIM))[lane] = o;
}

extern "C" void kernel_launch(void* const* d_in, const int* in_sizes, int n_in,
                              void* d_out, int out_size, void* d_ws, size_t ws_size,
                              hipStream_t stream) {
    const float* x  = (const float*)d_in[0];
    const int*   ei = (const int*)d_in[1];
    const float* Ws = (const float*)d_in[2];
    const float* bs = (const float*)d_in[3];

    const int N = in_sizes[0] / DIM;           // 100000
    const int E = in_sizes[1] / 2;             // 640000
    const int L = in_sizes[2] / (DIM * DIM);   // 3

    const int* src = ei;
    const int* dst = ei + E;

    float* out = (float*)d_out;

    char* ws = (char*)d_ws;
    unsigned short* Ab = (unsigned short*)ws;  ws += (size_t)N * DIM * 2;  // bf16 A', 25.6 MB
    short* Wb    = (short*)ws;                 ws += (size_t)L * 16384 * 2;
    float* dinv  = (float*)ws;                 ws += (size_t)N * 4;
    int*   cnt   = (int*)ws;                   ws += (size_t)N * 4;
    int*   incl  = (int*)ws;                   ws += (size_t)N * 4;
    int*   srcs  = (int*)ws;                   ws += (size_t)E * 4;
    int*   bsums = (int*)ws;                   ws += 512 * 4;

    const int nbN = (N + 255) / 256;           // 391 (< 512)
    const int nbE = (E + 255) / 256;
    const int totW = L * 16384;

    // ---- prepass: W fragments, degrees, CSR ----
    k_prepW<<<(totW + 255) / 256, 256, 0, stream>>>(Ws, Wb, totW);
    hipMemsetAsync(cnt, 0, (size_t)N * 4, stream);
    k_count<<<nbE, 256, 0, stream>>>(dst, cnt, E);
    k_dinv <<<nbN, 256, 0, stream>>>(cnt, dinv, N);
    k_scan1<<<nbN, 256, 0, stream>>>(cnt, incl, bsums, N);
    k_scan2<<<1, 512, 0, stream>>>(bsums, nbN);
    k_scan3<<<nbN, 256, 0, stream>>>(incl, bsums, N);
    k_fill <<<nbE, 256, 0, stream>>>(src, dst, incl, srcs, E);

    // ---- layers ----
    const float* h = x;
    for (int l = 0; l < L; ++l) {
        k_gemm_mfma<<<(N + 31) / 32, 256, 0, stream>>>(h, Wb + (size_t)l * 16384,
                                                       dinv, Ab, N);
        k_aggregate<<<(N + 3) / 4, 256, 0, stream>>>((const uint32*)Ab, srcs, incl, dinv,
                                                     bs + (size_t)l * DIM, out, N, E);
        h = out;
    }
}

// Round 6
// 353.063 us; speedup vs baseline: 10.7066x; 1.1266x over previous
//
#include <hip/hip_runtime.h>

#define DIM 128

typedef unsigned int uint32;
typedef short bf16x8 __attribute__((ext_vector_type(8)));
typedef float f32x4 __attribute__((ext_vector_type(4)));

__device__ __forceinline__ unsigned short f2b(float f) {
    return (unsigned short)((__float_as_uint(f) + 0x8000u) >> 16);
}
__device__ __forceinline__ uint32 packbf2(float lo, float hi) {
    uint32 a = __float_as_uint(lo);
    uint32 b = __float_as_uint(hi);
    return ((a + 0x8000u) >> 16) | ((b + 0x8000u) & 0xffff0000u);
}
__device__ __forceinline__ float bflo(uint32 u) { return __uint_as_float(u << 16); }
__device__ __forceinline__ float bfhi(uint32 u) { return __uint_as_float(u & 0xffff0000u); }

// ---------------- degree count ----------------
__global__ __launch_bounds__(256) void k_count(const int* __restrict__ dst,
                                               int* __restrict__ cnt, int E) {
    int e = blockIdx.x * 256 + threadIdx.x;
    if (e < E) atomicAdd(&cnt[dst[e]], 1);
}

__global__ __launch_bounds__(256) void k_dinv(const int* __restrict__ cnt,
                                              float* __restrict__ dinv, int n) {
    int i = blockIdx.x * 256 + threadIdx.x;
    if (i < n) dinv[i] = rsqrtf((float)(cnt[i] + 1));
}

// g0 = dinv ⊙ x, bf16-packed (uint = 2 cols)
__global__ __launch_bounds__(256) void k_scaleg(const float* __restrict__ x,
                                                const float* __restrict__ dinv,
                                                uint32* __restrict__ g, int n) {
    int t = blockIdx.x * 256 + threadIdx.x;   // over n*64 packed words
    if (t >= n * 64) return;
    int node = t >> 6;
    float dv = dinv[node];
    float2 v = ((const float2*)x)[t];
    g[t] = packbf2(dv * v.x, dv * v.y);
}

// ---------------- scan ----------------
__global__ __launch_bounds__(256) void k_scan1(const int* __restrict__ cnt,
                                               int* __restrict__ incl,
                                               int* __restrict__ bsums, int n) {
    __shared__ int tmp[256];
    int i = blockIdx.x * 256 + threadIdx.x;
    int t = threadIdx.x;
    tmp[t] = (i < n) ? cnt[i] : 0;
    __syncthreads();
#pragma unroll
    for (int off = 1; off < 256; off <<= 1) {
        int v = (t >= off) ? tmp[t - off] : 0;
        __syncthreads();
        tmp[t] += v;
        __syncthreads();
    }
    if (i < n) incl[i] = tmp[t];
    if (t == 255) bsums[blockIdx.x] = tmp[255];
}

__global__ __launch_bounds__(512) void k_scan2(int* __restrict__ bsums, int nb) {
    __shared__ int tmp[512];
    int t = threadIdx.x;
    tmp[t] = (t < nb) ? bsums[t] : 0;
    __syncthreads();
#pragma unroll
    for (int off = 1; off < 512; off <<= 1) {
        int v = (t >= off) ? tmp[t - off] : 0;
        __syncthreads();
        tmp[t] += v;
        __syncthreads();
    }
    if (t < nb) bsums[t] = (t == 0) ? 0 : tmp[t - 1];
}

__global__ __launch_bounds__(256) void k_scan3(int* __restrict__ incl,
                                               const int* __restrict__ bsums, int n) {
    int i = blockIdx.x * 256 + threadIdx.x;
    if (i < n) incl[i] += bsums[blockIdx.x];
}

// ---------------- CSR fill ----------------
__global__ __launch_bounds__(256) void k_fill(const int* __restrict__ src,
                                              const int* __restrict__ dst,
                                              int* __restrict__ incl,
                                              int* __restrict__ srcs, int E) {
    int e = blockIdx.x * 256 + threadIdx.x;
    if (e >= E) return;
    int p = atomicSub(&incl[dst[e]], 1) - 1;
    srcs[p] = src[e];
}

// ---------------- W -> per-lane bf16 B-fragments ----------------
// frag f = (w*2 + cs)*4 + ks ; element j, lane l:
//   n = w*32 + cs*16 + (l&15),  k = ks*32 + (l>>4)*8 + j
// (matches A-side: lane reads 8 contiguous k from m — any consistent A/B k-map is valid)
__global__ __launch_bounds__(256) void k_prepW(const float* __restrict__ Ws,
                                               short* __restrict__ Wb, int total) {
    int t = blockIdx.x * 256 + threadIdx.x;
    if (t >= total) return;
    int layer = t >> 14;
    int idx = t & 16383;
    int j = idx & 7;
    int l = (idx >> 3) & 63;
    int f = idx >> 9;          // 0..31
    int ks = f & 3;
    int cs = (f >> 2) & 1;
    int w = f >> 3;
    int nn = w * 32 + cs * 16 + (l & 15);
    int kk = ks * 32 + (l >> 4) * 8 + j;
    Wb[t] = (short)f2b(Ws[(size_t)layer * DIM * DIM + kk * DIM + nn]);
}

// ---------------- m[d] = dinv[d] * (g[d] + sum g[src]),  bf16 -> bf16 ----------------
// 2 nodes per wave: 32 lanes x 8B per row (256B coalesced gathers), 2 indep chains/wave.
__global__ __launch_bounds__(256) void k_aggregate(const uint32* __restrict__ g,
                                                   const int* __restrict__ srcs,
                                                   const int* __restrict__ rowptr,
                                                   const float* __restrict__ dinv,
                                                   uint32* __restrict__ m, int n, int E) {
    int tid = threadIdx.x;
    int node = blockIdx.x * 8 + ((tid >> 6) << 1) + ((tid >> 5) & 1);
    if (node >= n) return;
    int sub = tid & 31;
    int start = rowptr[node];
    int end = (node + 1 < n) ? rowptr[node + 1] : E;

    const uint2* g2 = (const uint2*)g;
    uint2 us = g2[(size_t)node * 32 + sub];
    float a0 = bflo(us.x), a1 = bfhi(us.x), a2 = bflo(us.y), a3 = bfhi(us.y);

    int p = start;
    for (; p + 4 <= end; p += 4) {
        int s0 = srcs[p + 0];
        int s1 = srcs[p + 1];
        int s2 = srcs[p + 2];
        int s3 = srcs[p + 3];
        uint2 u0 = g2[(size_t)s0 * 32 + sub];
        uint2 u1 = g2[(size_t)s1 * 32 + sub];
        uint2 u2 = g2[(size_t)s2 * 32 + sub];
        uint2 u3 = g2[(size_t)s3 * 32 + sub];
        a0 += bflo(u0.x) + bflo(u1.x) + bflo(u2.x) + bflo(u3.x);
        a1 += bfhi(u0.x) + bfhi(u1.x) + bfhi(u2.x) + bfhi(u3.x);
        a2 += bflo(u0.y) + bflo(u1.y) + bflo(u2.y) + bflo(u3.y);
        a3 += bfhi(u0.y) + bfhi(u1.y) + bfhi(u2.y) + bfhi(u3.y);
    }
    for (; p < end; ++p) {
        uint2 u = g2[(size_t)srcs[p] * 32 + sub];
        a0 += bflo(u.x);
        a1 += bfhi(u.x);
        a2 += bflo(u.y);
        a3 += bfhi(u.y);
    }

    float di = dinv[node];
    uint2 o;
    o.x = packbf2(di * a0, di * a1);
    o.y = packbf2(di * a2, di * a3);
    ((uint2*)m)[(size_t)node * 32 + sub] = o;
}

// ---------------- GEMM: z = m@W + b;  g_next = bf16(dinv*relu(z))  or  out = fp32 relu(z) ----------------
// block = 32 rows x 128 cols, 4 waves; wave w owns cols w*32..+31. No LDS; B-frags in regs;
// A read directly as bf16x8 (contiguous k) from m.
__global__ __launch_bounds__(256) void k_gemm_mfma(const unsigned short* __restrict__ M,
                                                   const short* __restrict__ Wb,
                                                   const float* __restrict__ dinv,
                                                   const float* __restrict__ bias,
                                                   unsigned short* __restrict__ Gn,
                                                   float* __restrict__ Out,
                                                   int n, int final_layer) {
    int tid = threadIdx.x;
    int w = tid >> 6;
    int l = tid & 63;
    int lr = l & 15;
    int lg = l >> 4;
    int row0 = blockIdx.x * 32;

    const bf16x8* wb = (const bf16x8*)Wb;
    bf16x8 bfrag[2][4];
#pragma unroll
    for (int cs = 0; cs < 2; ++cs)
#pragma unroll
        for (int ks = 0; ks < 4; ++ks)
            bfrag[cs][ks] = wb[((w * 2 + cs) * 4 + ks) * 64 + l];

    f32x4 acc[2][2];
#pragma unroll
    for (int rs = 0; rs < 2; ++rs)
#pragma unroll
        for (int cs = 0; cs < 2; ++cs) acc[rs][cs] = (f32x4){0.f, 0.f, 0.f, 0.f};

    int r0 = row0 + lr;
    int r1 = row0 + 16 + lr;
    bool ok0 = r0 < n, ok1 = r1 < n;
    const unsigned short* m0 = M + (size_t)r0 * DIM + lg * 8;
    const unsigned short* m1 = M + (size_t)r1 * DIM + lg * 8;

    const bf16x8 zf = (bf16x8){0, 0, 0, 0, 0, 0, 0, 0};
#pragma unroll
    for (int ks = 0; ks < 4; ++ks) {
        bf16x8 a0 = ok0 ? *(const bf16x8*)(m0 + ks * 32) : zf;
        bf16x8 a1 = ok1 ? *(const bf16x8*)(m1 + ks * 32) : zf;
#pragma unroll
        for (int cs = 0; cs < 2; ++cs) {
            acc[0][cs] = __builtin_amdgcn_mfma_f32_16x16x32_bf16(a0, bfrag[cs][ks], acc[0][cs], 0, 0, 0);
            acc[1][cs] = __builtin_amdgcn_mfma_f32_16x16x32_bf16(a1, bfrag[cs][ks], acc[1][cs], 0, 0, 0);
        }
    }

    float b0 = bias[w * 32 + lr];
    float b1 = bias[w * 32 + 16 + lr];

    // C/D layout (m89-verified): col = l&15, row = (l>>4)*4 + reg
#pragma unroll
    for (int rs = 0; rs < 2; ++rs)
#pragma unroll
        for (int r = 0; r < 4; ++r) {
            int grow = row0 + rs * 16 + lg * 4 + r;
            if (grow < n) {
                float h0 = fmaxf(acc[rs][0][r] + b0, 0.f);
                float h1 = fmaxf(acc[rs][1][r] + b1, 0.f);
                if (final_layer) {
                    Out[(size_t)grow * DIM + w * 32 + lr]      = h0;
                    Out[(size_t)grow * DIM + w * 32 + 16 + lr] = h1;
                } else {
                    float dv = dinv[grow];
                    Gn[(size_t)grow * DIM + w * 32 + lr]      = f2b(dv * h0);
                    Gn[(size_t)grow * DIM + w * 32 + 16 + lr] = f2b(dv * h1);
                }
            }
        }
}

extern "C" void kernel_launch(void* const* d_in, const int* in_sizes, int n_in,
                              void* d_out, int out_size, void* d_ws, size_t ws_size,
                              hipStream_t stream) {
    const float* x  = (const float*)d_in[0];
    const int*   ei = (const int*)d_in[1];
    const float* Ws = (const float*)d_in[2];
    const float* bs = (const float*)d_in[3];

    const int N = in_sizes[0] / DIM;           // 100000
    const int E = in_sizes[1] / 2;             // 640000
    const int L = in_sizes[2] / (DIM * DIM);   // 3

    const int* src = ei;
    const int* dst = ei + E;

    float* out = (float*)d_out;

    char* ws = (char*)d_ws;
    uint32* g    = (uint32*)ws;                ws += (size_t)N * 64 * 4;   // bf16 g, 25.6 MB
    uint32* m    = (uint32*)ws;                ws += (size_t)N * 64 * 4;   // bf16 m, 25.6 MB
    short* Wb    = (short*)ws;                 ws += (size_t)L * 16384 * 2;
    float* dinv  = (float*)ws;                 ws += (size_t)N * 4;
    int*   cnt   = (int*)ws;                   ws += (size_t)N * 4;
    int*   incl  = (int*)ws;                   ws += (size_t)N * 4;
    int*   srcs  = (int*)ws;                   ws += (size_t)E * 4;
    int*   bsums = (int*)ws;                   ws += 512 * 4;

    const int nbN = (N + 255) / 256;           // 391 (< 512)
    const int nbE = (E + 255) / 256;
    const int totW = L * 16384;

    // ---- prepass ----
    k_prepW<<<(totW + 255) / 256, 256, 0, stream>>>(Ws, Wb, totW);
    hipMemsetAsync(cnt, 0, (size_t)N * 4, stream);
    k_count<<<nbE, 256, 0, stream>>>(dst, cnt, E);
    k_dinv <<<nbN, 256, 0, stream>>>(cnt, dinv, N);
    k_scaleg<<<(N * 64 + 255) / 256, 256, 0, stream>>>(x, dinv, g, N);
    k_scan1<<<nbN, 256, 0, stream>>>(cnt, incl, bsums, N);
    k_scan2<<<1, 512, 0, stream>>>(bsums, nbN);
    k_scan3<<<nbN, 256, 0, stream>>>(incl, bsums, N);
    k_fill <<<nbE, 256, 0, stream>>>(src, dst, incl, srcs, E);

    // ---- layers: agg (g -> m), gemm (m -> g | out) ----
    for (int l = 0; l < L; ++l) {
        k_aggregate<<<(N + 7) / 8, 256, 0, stream>>>(g, srcs, incl, dinv, m, N, E);
        k_gemm_mfma<<<(N + 31) / 32, 256, 0, stream>>>((const unsigned short*)m,
                                                       Wb + (size_t)l * 16384, dinv,
                                                       bs + (size_t)l * DIM,
                                                       (unsigned short*)g, out,
                                                       N, l == L - 1);
    }
}

// Round 7
// 340.700 us; speedup vs baseline: 11.0951x; 1.0363x over previous
//
#include <hip/hip_runtime.h>

#define DIM 128
#define MROW 272   // LDS m-tile row stride in bytes (16B-aligned, bank-uniform)

typedef unsigned int uint32;
typedef short bf16x8 __attribute__((ext_vector_type(8)));
typedef float f32x4 __attribute__((ext_vector_type(4)));

__device__ __forceinline__ unsigned short f2b(float f) {
    return (unsigned short)((__float_as_uint(f) + 0x8000u) >> 16);
}
__device__ __forceinline__ uint32 packbf2(float lo, float hi) {
    uint32 a = __float_as_uint(lo);
    uint32 b = __float_as_uint(hi);
    return ((a + 0x8000u) >> 16) | ((b + 0x8000u) & 0xffff0000u);
}
__device__ __forceinline__ float bflo(uint32 u) { return __uint_as_float(u << 16); }
__device__ __forceinline__ float bfhi(uint32 u) { return __uint_as_float(u & 0xffff0000u); }

// ---------------- degree count ----------------
__global__ __launch_bounds__(256) void k_count(const int* __restrict__ dst,
                                               int* __restrict__ cnt, int E) {
    int e = blockIdx.x * 256 + threadIdx.x;
    if (e < E) atomicAdd(&cnt[dst[e]], 1);
}

// g0 = dinv ⊙ x, bf16-packed
__global__ __launch_bounds__(256) void k_scaleg(const float* __restrict__ x,
                                                const float* __restrict__ dinv,
                                                uint32* __restrict__ g, int n) {
    int t = blockIdx.x * 256 + threadIdx.x;
    if (t >= n * 64) return;
    int node = t >> 6;
    float dv = dinv[node];
    float2 v = ((const float2*)x)[t];
    g[t] = packbf2(dv * v.x, dv * v.y);
}

// ---------------- scan (+dinv fused) ----------------
__global__ __launch_bounds__(256) void k_scan1(const int* __restrict__ cnt,
                                               int* __restrict__ incl,
                                               int* __restrict__ bsums,
                                               float* __restrict__ dinv, int n) {
    __shared__ int tmp[256];
    int i = blockIdx.x * 256 + threadIdx.x;
    int t = threadIdx.x;
    int c = (i < n) ? cnt[i] : 0;
    if (i < n) dinv[i] = rsqrtf((float)(c + 1));
    tmp[t] = c;
    __syncthreads();
#pragma unroll
    for (int off = 1; off < 256; off <<= 1) {
        int v = (t >= off) ? tmp[t - off] : 0;
        __syncthreads();
        tmp[t] += v;
        __syncthreads();
    }
    if (i < n) incl[i] = tmp[t];
    if (t == 255) bsums[blockIdx.x] = tmp[255];
}

__global__ __launch_bounds__(512) void k_scan2(int* __restrict__ bsums, int nb) {
    __shared__ int tmp[512];
    int t = threadIdx.x;
    tmp[t] = (t < nb) ? bsums[t] : 0;
    __syncthreads();
#pragma unroll
    for (int off = 1; off < 512; off <<= 1) {
        int v = (t >= off) ? tmp[t - off] : 0;
        __syncthreads();
        tmp[t] += v;
        __syncthreads();
    }
    if (t < nb) bsums[t] = (t == 0) ? 0 : tmp[t - 1];
}

__global__ __launch_bounds__(256) void k_scan3(int* __restrict__ incl,
                                               const int* __restrict__ bsums, int n) {
    int i = blockIdx.x * 256 + threadIdx.x;
    if (i < n) incl[i] += bsums[blockIdx.x];
}

// ---------------- CSR fill ----------------
__global__ __launch_bounds__(256) void k_fill(const int* __restrict__ src,
                                              const int* __restrict__ dst,
                                              int* __restrict__ incl,
                                              int* __restrict__ srcs, int E) {
    int e = blockIdx.x * 256 + threadIdx.x;
    if (e >= E) return;
    int p = atomicSub(&incl[dst[e]], 1) - 1;
    srcs[p] = src[e];
}

// ---------------- W -> per-lane bf16 B-fragments ----------------
// frag f = (w*2 + cs)*4 + ks ; element j, lane l:
//   n = w*32 + cs*16 + (l&15),  k = ks*32 + (l>>4)*8 + j   (contiguous-k A-side match)
__global__ __launch_bounds__(256) void k_prepW(const float* __restrict__ Ws,
                                               short* __restrict__ Wb, int total) {
    int t = blockIdx.x * 256 + threadIdx.x;
    if (t >= total) return;
    int layer = t >> 14;
    int idx = t & 16383;
    int j = idx & 7;
    int l = (idx >> 3) & 63;
    int f = idx >> 9;
    int ks = f & 3;
    int cs = (f >> 2) & 1;
    int w = f >> 3;
    int nn = w * 32 + cs * 16 + (l & 15);
    int kk = ks * 32 + (l >> 4) * 8 + j;
    Wb[t] = (short)f2b(Ws[(size_t)layer * DIM * DIM + kk * DIM + nn]);
}

// ---------------- fused layer: aggregate 32 nodes -> LDS, then MFMA -> g_next|out ----------------
// phase 1: half-wave (32 lanes) aggregates 4 nodes sequentially; LDS row = bf16[128], stride 272B.
// phase 2: 4 waves x (32 rows x 32 cols strip) MFMA with register-resident B-fragments.
__global__ __launch_bounds__(256) void k_layer(const uint32* __restrict__ g,
                                               const int* __restrict__ srcs,
                                               const int* __restrict__ rowptr,
                                               const float* __restrict__ dinv,
                                               const short* __restrict__ Wb,
                                               const float* __restrict__ bias,
                                               uint32* __restrict__ Gn,
                                               float* __restrict__ Out,
                                               int n, int E, int final_layer) {
    __shared__ __align__(16) char smem[32 * MROW];   // 8.7 KB
    int tid = threadIdx.x;
    int row0 = blockIdx.x * 32;
    int w = tid >> 6;
    int l = tid & 63;
    int lr = l & 15;
    int lg = l >> 4;

    // preload B-fragments (independent of LDS; latency hides under gathers)
    const bf16x8* wb = (const bf16x8*)Wb;
    bf16x8 bfrag[2][4];
#pragma unroll
    for (int cs = 0; cs < 2; ++cs)
#pragma unroll
        for (int ks = 0; ks < 4; ++ks)
            bfrag[cs][ks] = wb[((w * 2 + cs) * 4 + ks) * 64 + l];

    // ---- phase 1: aggregate ----
    int hw = tid >> 5;      // half-wave 0..7
    int sub = tid & 31;
    const uint2* g2 = (const uint2*)g;
#pragma unroll
    for (int i = 0; i < 4; ++i) {
        int nl = hw * 4 + i;            // 0..31
        int node = row0 + nl;
        uint2 o = make_uint2(0u, 0u);
        if (node < n) {
            int start = rowptr[node];
            int end = (node + 1 < n) ? rowptr[node + 1] : E;
            uint2 us = g2[(size_t)node * 32 + sub];
            float a0 = bflo(us.x), a1 = bfhi(us.x), a2 = bflo(us.y), a3 = bfhi(us.y);
            int p = start;
            for (; p + 4 <= end; p += 4) {
                int s0 = srcs[p + 0];
                int s1 = srcs[p + 1];
                int s2 = srcs[p + 2];
                int s3 = srcs[p + 3];
                uint2 u0 = g2[(size_t)s0 * 32 + sub];
                uint2 u1 = g2[(size_t)s1 * 32 + sub];
                uint2 u2 = g2[(size_t)s2 * 32 + sub];
                uint2 u3 = g2[(size_t)s3 * 32 + sub];
                a0 += bflo(u0.x) + bflo(u1.x) + bflo(u2.x) + bflo(u3.x);
                a1 += bfhi(u0.x) + bfhi(u1.x) + bfhi(u2.x) + bfhi(u3.x);
                a2 += bflo(u0.y) + bflo(u1.y) + bflo(u2.y) + bflo(u3.y);
                a3 += bfhi(u0.y) + bfhi(u1.y) + bfhi(u2.y) + bfhi(u3.y);
            }
            for (; p < end; ++p) {
                uint2 u = g2[(size_t)srcs[p] * 32 + sub];
                a0 += bflo(u.x);
                a1 += bfhi(u.x);
                a2 += bflo(u.y);
                a3 += bfhi(u.y);
            }
            float di = dinv[node];
            o.x = packbf2(di * a0, di * a1);
            o.y = packbf2(di * a2, di * a3);
        }
        *(uint2*)(smem + nl * MROW + sub * 8) = o;   // cols sub*4..sub*4+3
    }
    __syncthreads();

    // ---- phase 2: MFMA ----
    f32x4 acc[2][2];
#pragma unroll
    for (int rs = 0; rs < 2; ++rs)
#pragma unroll
        for (int cs = 0; cs < 2; ++cs) acc[rs][cs] = (f32x4){0.f, 0.f, 0.f, 0.f};

    const char* base0 = smem + lr * MROW + lg * 16;
    const char* base1 = smem + (16 + lr) * MROW + lg * 16;
#pragma unroll
    for (int ks = 0; ks < 4; ++ks) {
        bf16x8 a0 = *(const bf16x8*)(base0 + ks * 64);
        bf16x8 a1 = *(const bf16x8*)(base1 + ks * 64);
#pragma unroll
        for (int cs = 0; cs < 2; ++cs) {
            acc[0][cs] = __builtin_amdgcn_mfma_f32_16x16x32_bf16(a0, bfrag[cs][ks], acc[0][cs], 0, 0, 0);
            acc[1][cs] = __builtin_amdgcn_mfma_f32_16x16x32_bf16(a1, bfrag[cs][ks], acc[1][cs], 0, 0, 0);
        }
    }

    float b0 = bias[w * 32 + lr];
    float b1 = bias[w * 32 + 16 + lr];

    // C/D layout (m89-verified): col = l&15, row = (l>>4)*4 + reg
#pragma unroll
    for (int rs = 0; rs < 2; ++rs)
#pragma unroll
        for (int r = 0; r < 4; ++r) {
            int grow = row0 + rs * 16 + lg * 4 + r;
            if (grow < n) {
                float h0 = fmaxf(acc[rs][0][r] + b0, 0.f);
                float h1 = fmaxf(acc[rs][1][r] + b1, 0.f);
                if (final_layer) {
                    Out[(size_t)grow * DIM + w * 32 + lr]      = h0;
                    Out[(size_t)grow * DIM + w * 32 + 16 + lr] = h1;
                } else {
                    float dv = dinv[grow];
                    unsigned short* gp = (unsigned short*)Gn;
                    gp[(size_t)grow * DIM + w * 32 + lr]      = f2b(dv * h0);
                    gp[(size_t)grow * DIM + w * 32 + 16 + lr] = f2b(dv * h1);
                }
            }
        }
}

extern "C" void kernel_launch(void* const* d_in, const int* in_sizes, int n_in,
                              void* d_out, int out_size, void* d_ws, size_t ws_size,
                              hipStream_t stream) {
    const float* x  = (const float*)d_in[0];
    const int*   ei = (const int*)d_in[1];
    const float* Ws = (const float*)d_in[2];
    const float* bs = (const float*)d_in[3];

    const int N = in_sizes[0] / DIM;           // 100000
    const int E = in_sizes[1] / 2;             // 640000
    const int L = in_sizes[2] / (DIM * DIM);   // 3

    const int* src = ei;
    const int* dst = ei + E;

    float* out = (float*)d_out;

    char* ws = (char*)d_ws;
    uint32* g0   = (uint32*)ws;                ws += (size_t)N * 64 * 4;   // 25.6 MB
    uint32* g1   = (uint32*)ws;                ws += (size_t)N * 64 * 4;   // 25.6 MB
    short* Wb    = (short*)ws;                 ws += (size_t)L * 16384 * 2;
    float* dinv  = (float*)ws;                 ws += (size_t)N * 4;
    int*   cnt   = (int*)ws;                   ws += (size_t)N * 4;
    int*   incl  = (int*)ws;                   ws += (size_t)N * 4;
    int*   srcs  = (int*)ws;                   ws += (size_t)E * 4;
    int*   bsums = (int*)ws;                   ws += 512 * 4;

    const int nbN = (N + 255) / 256;           // 391 (< 512)
    const int nbE = (E + 255) / 256;
    const int totW = L * 16384;

    // ---- prepass ----
    k_prepW<<<(totW + 255) / 256, 256, 0, stream>>>(Ws, Wb, totW);
    hipMemsetAsync(cnt, 0, (size_t)N * 4, stream);
    k_count<<<nbE, 256, 0, stream>>>(dst, cnt, E);
    k_scan1<<<nbN, 256, 0, stream>>>(cnt, incl, bsums, dinv, N);
    k_scan2<<<1, 512, 0, stream>>>(bsums, nbN);
    k_scaleg<<<(N * 64 + 255) / 256, 256, 0, stream>>>(x, dinv, g0, N);
    k_scan3<<<nbN, 256, 0, stream>>>(incl, bsums, N);
    k_fill <<<nbE, 256, 0, stream>>>(src, dst, incl, srcs, E);

    // ---- fused layers: g -> (agg in LDS) -> MFMA -> g'|out ----
    const int nblk = (N + 31) / 32;
    uint32* gin = g0;
    for (int l = 0; l < L; ++l) {
        uint32* gout = (gin == g0) ? g1 : g0;
        k_layer<<<nblk, 256, 0, stream>>>(gin, srcs, incl, dinv,
                                          Wb + (size_t)l * 16384,
                                          bs + (size_t)l * DIM,
                                          gout, out, N, E, l == L - 1);
        gin = gout;
    }
}